// Round 2
// baseline (7610.434 us; speedup 1.0000x reference)
//
#include <hip/hip_runtime.h>
#include <stdint.h>

// DagCellTorch: T=128 steps, B=512 rows, nhid=ninp=256.
// Row-independent recurrence -> 256 blocks x 2 rows, no inter-block sync.
// Weights pre-packed to bf16 pairs (k-major) in d_ws; h kept f32 in LDS.

#define T_STEPS 128
#define B_ROWS  512
#define NH      256
#define NPAIRS  9   // (wxc,wxh), (whc,whh), (Wc[e],Wh[e]) e=0..6

__device__ __forceinline__ float sigmoidf_(float x){
  float e = __expf(-fabsf(x));
  float s = 1.f/(1.f+e);
  return x>=0.f ? s : 1.f-s;
}
__device__ __forceinline__ float tanhf_(float x){
  float e = __expf(-2.f*fabsf(x));
  float r = (1.f-e)/(1.f+e);
  return x>=0.f ? r : -r;
}
__device__ __forceinline__ unsigned short f2bf(float f){
  uint32_t u = __float_as_uint(f);
  uint32_t r = (u + 0x7fffu + ((u>>16)&1u)) >> 16;   // round-to-nearest-even
  return (unsigned short)r;
}

// Pack pair p at [p][k][n]: low16 = bf16(A[n][k]) (c-gate mat), high16 = bf16(B[n][k]) (h mat)
__global__ void prep_weights(const float* __restrict__ wxc, const float* __restrict__ wxh,
                             const float* __restrict__ whc, const float* __restrict__ whh,
                             const float* __restrict__ Wc,  const float* __restrict__ Wh,
                             uint32_t* __restrict__ WPK){
  int idx = blockIdx.x*256 + threadIdx.x;
  if (idx >= NPAIRS*NH*NH) return;
  int p = idx >> 16;
  int k = (idx >> 8) & 255;
  int n = idx & 255;
  const float *A, *B;
  if (p == 0)      { A = wxc; B = wxh; }
  else if (p == 1) { A = whc; B = whh; }
  else             { A = Wc + (size_t)(p-2)*NH*NH; B = Wh + (size_t)(p-2)*NH*NH; }
  float a = A[(size_t)n*NH + k];
  float b = B[(size_t)n*NH + k];
  WPK[idx] = ((uint32_t)f2bf(b) << 16) | (uint32_t)f2bf(a);
}

// One pair-stream: oa[r] = sum_k in[k].r * A[n=j][k], ob likewise for B.
// wp is pre-offset by thread's column j; stride NH dwords per k.
__device__ __forceinline__ void stream_pair(const uint32_t* __restrict__ wp,
                                            const float2* __restrict__ in,
                                            float2* __restrict__ oa, float2* __restrict__ ob){
  float ax=0.f, ay=0.f, bx=0.f, by=0.f;
  #pragma unroll 8
  for (int k=0; k<NH; ++k){
    uint32_t u = wp[k*NH];
    float2 iv = in[k];
    float wa = __uint_as_float(u << 16);          // low16 -> A
    float wb = __uint_as_float(u & 0xffff0000u);  // high16 -> B
    ax = fmaf(iv.x, wa, ax);
    ay = fmaf(iv.y, wa, ay);
    bx = fmaf(iv.x, wb, bx);
    by = fmaf(iv.y, wb, by);
  }
  *oa = make_float2(ax, ay);
  *ob = make_float2(bx, by);
}

template<int ACT>  // 0 relu, 1 tanh, 2 sigmoid, 3 identity
__device__ __forceinline__ float2 edge_combine(float2 cpre, float2 hpre, float2 hold){
  float ca = sigmoidf_(cpre.x), cb = sigmoidf_(cpre.y);
  float fa, fb;
  if constexpr (ACT==0){ fa = fmaxf(hpre.x,0.f); fb = fmaxf(hpre.y,0.f); }
  else if constexpr (ACT==1){ fa = tanhf_(hpre.x); fb = tanhf_(hpre.y); }
  else if constexpr (ACT==2){ fa = sigmoidf_(hpre.x); fb = sigmoidf_(hpre.y); }
  else { fa = hpre.x; fb = hpre.y; }
  return make_float2(ca*fa + (1.f-ca)*hold.x, cb*fb + (1.f-cb)*hold.y);
}

__global__ __launch_bounds__(256) void dag_main(
    const float* __restrict__ x,    // (T,B,NH)
    const float* __restrict__ h0,   // (B,NH)
    const float* __restrict__ bxc,  // (NH)
    const float* __restrict__ bxh,  // (NH)
    const uint32_t* __restrict__ WPK,
    float* __restrict__ out)        // T*B*NH outputs then B*NH final hidden
{
  __shared__ float2 hbuf[2][NH];   // [buf][col] = {row0, row1}, f32
  __shared__ float2 xbuf[NH];
  __shared__ float  red[4][2];
  const int j    = threadIdx.x;
  const int r0   = blockIdx.x * 2;
  const int lane = j & 63, wv = j >> 6;
  const uint32_t* wpj = WPK + j;

  hbuf[0][j] = make_float2(h0[(size_t)r0*NH + j], h0[(size_t)(r0+1)*NH + j]);
  const float bc = bxc[j], bh = bxh[j];
  __syncthreads();

  for (int t=0; t<T_STEPS; ++t){
    xbuf[j] = make_float2(x[((size_t)t*B_ROWS + r0    )*NH + j],
                          x[((size_t)t*B_ROWS + r0 + 1)*NH + j]);
    __syncthreads();

    // ---- node 0: c0 = sig(xWxc^T+bc + hWhc^T); h = c0*tanh(xWxh^T+bh + hWhh^T)+(1-c0)h
    float2 xc, xh, hc, hh;
    stream_pair(wpj + 0*NH*NH, xbuf,    &xc, &xh);
    stream_pair(wpj + 1*NH*NH, hbuf[0], &hc, &hh);
    float2 hold = hbuf[0][j];
    float c0a = sigmoidf_(xc.x + bc + hc.x);
    float c0b = sigmoidf_(xc.y + bc + hc.y);
    float2 hn = make_float2(c0a*tanhf_(xh.x + bh + hh.x) + (1.f-c0a)*hold.x,
                            c0b*tanhf_(xh.y + bh + hh.y) + (1.f-c0b)*hold.y);
    hbuf[1][j] = hn;  __syncthreads();

    float2 cp, hp;
    // ---- edge 0 (relu): read b1 -> write b0
    stream_pair(wpj + 2*NH*NH, hbuf[1], &cp, &hp);
    hn = edge_combine<0>(cp, hp, hbuf[1][j]);
    hbuf[0][j] = hn;  __syncthreads();
    // ---- edge 1 (tanh): b0 -> b1
    stream_pair(wpj + 3*NH*NH, hbuf[0], &cp, &hp);
    hn = edge_combine<1>(cp, hp, hbuf[0][j]);
    hbuf[1][j] = hn;  __syncthreads();
    // ---- edge 2 (sigmoid): b1 -> b0
    stream_pair(wpj + 4*NH*NH, hbuf[1], &cp, &hp);
    hn = edge_combine<2>(cp, hp, hbuf[1][j]);
    hbuf[0][j] = hn;  __syncthreads();
    // ---- edge 3 (identity): b0 -> b1
    stream_pair(wpj + 5*NH*NH, hbuf[0], &cp, &hp);
    hn = edge_combine<3>(cp, hp, hbuf[0][j]);
    hbuf[1][j] = hn;  __syncthreads();
    // ---- edge 4 (relu): b1 -> b0
    stream_pair(wpj + 6*NH*NH, hbuf[1], &cp, &hp);
    hn = edge_combine<0>(cp, hp, hbuf[1][j]);
    hbuf[0][j] = hn;  __syncthreads();
    // ---- edge 5 (tanh): b0 -> b1
    stream_pair(wpj + 7*NH*NH, hbuf[0], &cp, &hp);
    hn = edge_combine<1>(cp, hp, hbuf[0][j]);
    hbuf[1][j] = hn;  __syncthreads();
    // ---- edge 6 (identity) + norm clip: b1 -> b0
    stream_pair(wpj + 8*NH*NH, hbuf[1], &cp, &hp);
    hn = edge_combine<3>(cp, hp, hbuf[1][j]);

    float p0 = hn.x*hn.x, p1 = hn.y*hn.y;
    #pragma unroll
    for (int off=32; off; off>>=1){ p0 += __shfl_xor(p0, off); p1 += __shfl_xor(p1, off); }
    if (lane==0){ red[wv][0]=p0; red[wv][1]=p1; }
    __syncthreads();
    float n0 = sqrtf(red[0][0]+red[1][0]+red[2][0]+red[3][0]);
    float n1 = sqrtf(red[0][1]+red[1][1]+red[2][1]+red[3][1]);
    float s0 = (n0 > 25.f) ? 25.f/n0 : 1.f;
    float s1 = (n1 > 25.f) ? 25.f/n1 : 1.f;
    hn.x *= s0; hn.y *= s1;
    hbuf[0][j] = hn;
    size_t ob = (size_t)t*(B_ROWS*NH);
    out[ob + (size_t)r0*NH + j]     = hn.x;
    out[ob + (size_t)(r0+1)*NH + j] = hn.y;
    __syncthreads();
  }

  float2 hf = hbuf[0][j];
  out[(size_t)T_STEPS*(B_ROWS*NH) + (size_t)r0*NH + j]     = hf.x;
  out[(size_t)T_STEPS*(B_ROWS*NH) + (size_t)(r0+1)*NH + j] = hf.y;
}

extern "C" void kernel_launch(void* const* d_in, const int* in_sizes, int n_in,
                              void* d_out, int out_size, void* d_ws, size_t ws_size,
                              hipStream_t stream) {
  const float* x   = (const float*)d_in[0];
  const float* h0  = (const float*)d_in[1];
  const float* wxc = (const float*)d_in[2];
  const float* bxc = (const float*)d_in[3];
  const float* wxh = (const float*)d_in[4];
  const float* bxh = (const float*)d_in[5];
  const float* whc = (const float*)d_in[6];
  const float* whh = (const float*)d_in[7];
  const float* Wc  = (const float*)d_in[8];
  const float* Wh  = (const float*)d_in[9];
  uint32_t* WPK = (uint32_t*)d_ws;   // 9*256*256*4 = 2.25 MB

  prep_weights<<<(NPAIRS*NH*NH + 255)/256, 256, 0, stream>>>(wxc, wxh, whc, whh, Wc, Wh, WPK);
  dag_main<<<B_ROWS/2, 256, 0, stream>>>(x, h0, bxc, bxh, WPK, (float*)d_out);
}

// Round 5
// 4787.523 us; speedup vs baseline: 1.5896x; 1.5896x over previous
//
#include <hip/hip_runtime.h>
#include <stdint.h>

// DagCellTorch R5: 256 blocks x 512 threads, thread = (row r in {0,1}, col j).
// Weights bf16 k-quad packed (uint4 = 4k x {A,B}) streamed from L2.
// h carried f32 (LDS hf) and fed to v_dot2_f32_bf16 as hi/lo split-bf16
// (numerically f32-accurate, matches the R2-accuracy data path).

#define T_STEPS 128
#define B_ROWS  512
#define NH      256
#define NPAIRS  9   // p=0:(wxc,wxh), p=1:(whc,whh), p=2..8: edges 0..6
#define KQ      64  // k-quads (4 k per quad)

__device__ __forceinline__ float sigmoidf_(float x){
  float e = __expf(-fabsf(x));
  float s = 1.f/(1.f+e);
  return x>=0.f ? s : 1.f-s;
}
__device__ __forceinline__ float tanhf_(float x){
  float e = __expf(-2.f*fabsf(x));
  float r = (1.f-e)/(1.f+e);
  return x>=0.f ? r : -r;
}
__device__ __forceinline__ unsigned short f2bf(float f){
  uint32_t u = __float_as_uint(f);
  uint32_t r = (u + 0x7fffu + ((u>>16)&1u)) >> 16;   // RNE
  return (unsigned short)r;
}
__device__ __forceinline__ uint32_t packbf(float a, float b){
  return (uint32_t)f2bf(a) | ((uint32_t)f2bf(b) << 16);
}
__device__ __forceinline__ float bfhi(float f){
  return __uint_as_float((uint32_t)f2bf(f) << 16);
}
__device__ __forceinline__ float dot2bf(uint32_t a, uint32_t b, float c){
  float d;
  asm("v_dot2_f32_bf16 %0, %1, %2, %3" : "=v"(d) : "v"(a), "v"(b), "v"(c));
  return d;
}

// WQ[(((p*KQ + kq)*NH + n)*4 + c)]: c0=A k(4kq,4kq+1), c1=B same, c2=A k(4kq+2,+3), c3=B same
__global__ void prep_weights(const float* __restrict__ wxc, const float* __restrict__ wxh,
                             const float* __restrict__ whc, const float* __restrict__ whh,
                             const float* __restrict__ Wc,  const float* __restrict__ Wh,
                             uint32_t* __restrict__ WQ){
  int idx = blockIdx.x*256 + threadIdx.x;
  if (idx >= NPAIRS*KQ*NH*4) return;
  int p   = idx >> 16;
  int rem = idx & 65535;
  int kq  = rem >> 10;
  int n   = (rem >> 2) & 255;
  int c   = rem & 3;
  int mat = c & 1;
  int k0  = 4*kq + 2*(c>>1);
  const float *A, *B;
  if (p == 0)      { A = wxc; B = wxh; }
  else if (p == 1) { A = whc; B = whh; }
  else             { A = Wc + (size_t)(p-2)*NH*NH; B = Wh + (size_t)(p-2)*NH*NH; }
  const float* M = mat ? B : A;
  WQ[idx] = packbf(M[(size_t)n*NH + k0], M[(size_t)n*NH + k0 + 1]);
}

// accA += sum_k src_k*A[j][k], accB likewise, with src = hi/lo split-bf16 quads:
// src[kq] = {hi(4kq,4kq+1), hi(4kq+2,4kq+3), lo(4kq,4kq+1), lo(4kq+2,4kq+3)}
__device__ __forceinline__ void stream_q(const uint4* __restrict__ wj,
                                         const uint4* __restrict__ src,
                                         float& accA, float& accB){
  float a0=0.f,b0=0.f,a1=0.f,b1=0.f,a2=0.f,b2=0.f,a3=0.f,b3=0.f;
  #pragma unroll 8
  for (int kq = 0; kq < KQ; ++kq){
    uint4 w  = wj[(size_t)kq*NH];
    uint4 hv = src[kq];
    a0 = dot2bf(w.x, hv.x, a0);  b0 = dot2bf(w.y, hv.x, b0);
    a1 = dot2bf(w.z, hv.y, a1);  b1 = dot2bf(w.w, hv.y, b1);
    a2 = dot2bf(w.x, hv.z, a2);  b2 = dot2bf(w.y, hv.z, b2);
    a3 = dot2bf(w.z, hv.w, a3);  b3 = dot2bf(w.w, hv.w, b3);
  }
  accA += (a0 + a1) + (a2 + a3);
  accB += (b0 + b1) + (b2 + b3);
}

template<int ACT>  // 0 relu, 1 tanh, 2 sigmoid, 3 identity
__device__ __forceinline__ float edge_hn(const uint4* __restrict__ wj,
                                         const uint4* __restrict__ src, float hold){
  float accA = 0.f, accB = 0.f;
  stream_q(wj, src, accA, accB);
  float c = sigmoidf_(accA);
  float f;
  if constexpr (ACT==0)      f = fmaxf(accB, 0.f);
  else if constexpr (ACT==1) f = tanhf_(accB);
  else if constexpr (ACT==2) f = sigmoidf_(accB);
  else                       f = accB;
  return c*f + (1.f-c)*hold;
}

__global__ __launch_bounds__(512) void dag_main(
    const float* __restrict__ x,    // (T,B,NH) f32
    const float* __restrict__ h0,   // (B,NH) f32
    const float* __restrict__ bxc,  // (NH)
    const float* __restrict__ bxh,  // (NH)
    const uint32_t* __restrict__ WQ,
    float* __restrict__ out)        // T*B*NH outputs then B*NH final hidden
{
  __shared__ float hf[2][NH];     // f32 h (single buffer, own-slot RMW)
  __shared__ uint4 hq[2][KQ];     // hi/lo split-bf16 h quads
  __shared__ uint4 xq[2][KQ];     // hi/lo split-bf16 x_t quads
  __shared__ float red[8];

  const int tid = threadIdx.x;
  const int j   = tid & 255;      // output column
  const int r   = tid >> 8;       // row within block
  const int wv  = tid >> 6;
  const int r0  = blockIdx.x * 2;
  const uint4* WQ4 = (const uint4*)WQ;

  // pack-slot mapping (one dword per thread): rr=tid>>8, kq=(tid>>2)&63, c=tid&3
  const int prr = tid >> 8;
  const int pc  = tid & 3;
  const int pk0 = ((tid >> 2) & 63)*4 + 2*(pc & 1);

  const float bc = bxc[j], bh = bxh[j];

  hf[r][j] = h0[(size_t)(r0 + r)*NH + j];
  __syncthreads();
  // initial packs: hq from hf, xq from x[t=0]
  {
    float2 hp = *(const float2*)&hf[prr][pk0];
    uint32_t d = (pc < 2) ? packbf(hp.x, hp.y)
                          : packbf(hp.x - bfhi(hp.x), hp.y - bfhi(hp.y));
    ((uint32_t*)hq)[tid] = d;
    const float2 xv = *(const float2*)&x[(size_t)(r0 + prr)*NH + pk0];
    uint32_t dx = (pc < 2) ? packbf(xv.x, xv.y)
                           : packbf(xv.x - bfhi(xv.x), xv.y - bfhi(xv.y));
    ((uint32_t*)xq)[tid] = dx;
  }
  __syncthreads();

  for (int t = 0; t < T_STEPS; ++t){
    // ---- node 0
    {
      float accA = 0.f, accB = 0.f;
      stream_q(WQ4 + (size_t)0*KQ*NH + j, xq[r], accA, accB);
      stream_q(WQ4 + (size_t)1*KQ*NH + j, hq[r], accA, accB);
      float hold = hf[r][j];
      float c0 = sigmoidf_(accA + bc);
      float f0 = tanhf_(accB + bh);
      hf[r][j] = c0*f0 + (1.f-c0)*hold;
    }
    __syncthreads();
    {
      float2 hp = *(const float2*)&hf[prr][pk0];
      ((uint32_t*)hq)[tid] = (pc < 2) ? packbf(hp.x, hp.y)
                                      : packbf(hp.x - bfhi(hp.x), hp.y - bfhi(hp.y));
    }
    __syncthreads();

    // ---- edges 0..5 (ACTS[1..6] = relu, tanh, sigmoid, identity, relu, tanh)
    #define EDGE_STAGE(P, ACT)                                                   \
    hf[r][j] = edge_hn<ACT>(WQ4 + (size_t)(P)*KQ*NH + j, hq[r], hf[r][j]);       \
    __syncthreads();                                                             \
    {                                                                            \
      float2 hp = *(const float2*)&hf[prr][pk0];                                 \
      ((uint32_t*)hq)[tid] = (pc < 2) ? packbf(hp.x, hp.y)                       \
                                      : packbf(hp.x - bfhi(hp.x), hp.y - bfhi(hp.y)); \
    }                                                                            \
    __syncthreads();

    EDGE_STAGE(2, 0)
    EDGE_STAGE(3, 1)
    EDGE_STAGE(4, 2)
    EDGE_STAGE(5, 3)
    EDGE_STAGE(6, 0)
    EDGE_STAGE(7, 1)
    #undef EDGE_STAGE

    // ---- edge 6 (identity) + norm clip + output write
    {
      float hn = edge_hn<3>(WQ4 + (size_t)8*KQ*NH + j, hq[r], hf[r][j]);
      float pw = hn*hn;
      #pragma unroll
      for (int off = 32; off; off >>= 1) pw += __shfl_xor(pw, off);
      if ((tid & 63) == 0) red[wv] = pw;
      __syncthreads();
      float s2  = red[r*4] + red[r*4+1] + red[r*4+2] + red[r*4+3];
      float nrm = sqrtf(s2);
      float sc  = (nrm > 25.f) ? 25.f/nrm : 1.f;
      float hv  = hn * sc;
      out[(size_t)t*(B_ROWS*NH) + (size_t)(r0+r)*NH + j] = hv;
      hf[r][j] = hv;
    }
    __syncthreads();
    {
      float2 hp = *(const float2*)&hf[prr][pk0];
      ((uint32_t*)hq)[tid] = (pc < 2) ? packbf(hp.x, hp.y)
                                      : packbf(hp.x - bfhi(hp.x), hp.y - bfhi(hp.y));
      if (t + 1 < T_STEPS){
        const float2 xv = *(const float2*)&x[((size_t)(t+1)*B_ROWS + r0 + prr)*NH + pk0];
        ((uint32_t*)xq)[tid] = (pc < 2) ? packbf(xv.x, xv.y)
                                        : packbf(xv.x - bfhi(xv.x), xv.y - bfhi(xv.y));
      }
    }
    __syncthreads();
  }

  out[(size_t)T_STEPS*(B_ROWS*NH) + (size_t)(r0+r)*NH + j] = hf[r][j];
}

extern "C" void kernel_launch(void* const* d_in, const int* in_sizes, int n_in,
                              void* d_out, int out_size, void* d_ws, size_t ws_size,
                              hipStream_t stream) {
  const float* x   = (const float*)d_in[0];
  const float* h0  = (const float*)d_in[1];
  const float* wxc = (const float*)d_in[2];
  const float* bxc = (const float*)d_in[3];
  const float* wxh = (const float*)d_in[4];
  const float* bxh = (const float*)d_in[5];
  const float* whc = (const float*)d_in[6];
  const float* whh = (const float*)d_in[7];
  const float* Wc  = (const float*)d_in[8];
  const float* Wh  = (const float*)d_in[9];
  uint32_t* WQ = (uint32_t*)d_ws;   // 9*64*256*4 dwords = 2.36 MB

  const int total = NPAIRS*KQ*NH*4;
  prep_weights<<<(total + 255)/256, 256, 0, stream>>>(wxc, wxh, whc, whh, Wc, Wh, WQ);
  dag_main<<<B_ROWS/2, 512, 0, stream>>>(x, h0, bxc, bxh, WQ, (float*)d_out);
}

// Round 6
// 3937.962 us; speedup vs baseline: 1.9326x; 1.2157x over previous
//
#include <hip/hip_runtime.h>
#include <hip/hip_fp16.h>
#include <stdint.h>

// DagCellTorch R6: 128 blocks x 1024 threads. BM=4 rows/block.
// thread = (s: k-quarter 0..3, j: col 0..255), each handles all 4 rows.
// Weights + h + x in fp16 (RNE), v_dot2_f32_f16, f32 accumulate/state.
// h state lives in finalize-thread registers; fp16 pack via __shfl.

#define T_STEPS 128
#define B_ROWS  512
#define NH      256
#define NPAIRS  9     // p=0:(wxc,wxh), p=1:(whc,whh), p=2..8: edges 0..6
#define KQ      64    // k-quads (4 k each)
#define BM      4
#define NBLK    (B_ROWS/BM)   // 128
#define NTHR    1024
#define SQ      4     // k-split
#define QPS     (KQ/SQ)       // 16 quads per thread per stream

__device__ __forceinline__ float sigmoidf_(float x){
  float e = __expf(-fabsf(x));
  float s = 1.f/(1.f+e);
  return x>=0.f ? s : 1.f-s;
}
__device__ __forceinline__ float tanhf_(float x){
  float e = __expf(-2.f*fabsf(x));
  float r = (1.f-e)/(1.f+e);
  return x>=0.f ? r : -r;
}
__device__ __forceinline__ unsigned short f2h(float f){
  return __half_as_ushort(__float2half(f));   // RNE
}
__device__ __forceinline__ uint32_t packh(float a, float b){
  return (uint32_t)f2h(a) | ((uint32_t)f2h(b) << 16);
}
__device__ __forceinline__ float fdot2_(uint32_t a, uint32_t b, float c){
  float d;
  asm("v_dot2_f32_f16 %0, %1, %2, %3" : "=v"(d) : "v"(a), "v"(b), "v"(c));
  return d;
}

// WQ[(((p*KQ + kq)*NH + n)*4 + c)]: c0=A k(4kq,4kq+1), c1=B same, c2=A k(+2,+3), c3=B same
__global__ void prep_weights(const float* __restrict__ wxc, const float* __restrict__ wxh,
                             const float* __restrict__ whc, const float* __restrict__ whh,
                             const float* __restrict__ Wc,  const float* __restrict__ Wh,
                             uint32_t* __restrict__ WQ){
  int idx = blockIdx.x*256 + threadIdx.x;
  if (idx >= NPAIRS*KQ*NH*4) return;
  int p   = idx >> 16;
  int rem = idx & 65535;
  int kq  = rem >> 10;
  int n   = (rem >> 2) & 255;
  int c   = rem & 3;
  int mat = c & 1;
  int k0  = 4*kq + 2*(c>>1);
  const float *A, *B;
  if (p == 0)      { A = wxc; B = wxh; }
  else if (p == 1) { A = whc; B = whh; }
  else             { A = Wc + (size_t)(p-2)*NH*NH; B = Wh + (size_t)(p-2)*NH*NH; }
  const float* M = mat ? B : A;
  WQ[idx] = packh(M[(size_t)n*NH + k0], M[(size_t)n*NH + k0 + 1]);
}

template<int ACT>  // 0 relu, 1 tanh, 2 sigmoid, 3 identity
__device__ __forceinline__ float actf(float v){
  if constexpr (ACT==0)      return fmaxf(v, 0.f);
  else if constexpr (ACT==1) return tanhf_(v);
  else if constexpr (ACT==2) return sigmoidf_(v);
  else                       return v;
}

// acc[r*4+0]=A k01, +1=A k23, +2=B k01, +3=B k23  (r = row 0..3)
__device__ __forceinline__ void stream16(const uint4* __restrict__ wp,
                                         const uint4 (* __restrict__ src)[2],
                                         int qb, float* acc){
  #pragma unroll 4
  for (int q = 0; q < QPS; ++q){
    const uint4 w  = wp[(size_t)q*NH];
    const uint4 ha = src[qb+q][0];   // r0:{k01,k23}, r1:{k01,k23}
    const uint4 hb = src[qb+q][1];   // r2, r3
    acc[0]  = fdot2_(w.x, ha.x, acc[0]);
    acc[1]  = fdot2_(w.z, ha.y, acc[1]);
    acc[2]  = fdot2_(w.y, ha.x, acc[2]);
    acc[3]  = fdot2_(w.w, ha.y, acc[3]);
    acc[4]  = fdot2_(w.x, ha.z, acc[4]);
    acc[5]  = fdot2_(w.z, ha.w, acc[5]);
    acc[6]  = fdot2_(w.y, ha.z, acc[6]);
    acc[7]  = fdot2_(w.w, ha.w, acc[7]);
    acc[8]  = fdot2_(w.x, hb.x, acc[8]);
    acc[9]  = fdot2_(w.z, hb.y, acc[9]);
    acc[10] = fdot2_(w.y, hb.x, acc[10]);
    acc[11] = fdot2_(w.w, hb.y, acc[11]);
    acc[12] = fdot2_(w.x, hb.z, acc[12]);
    acc[13] = fdot2_(w.z, hb.w, acc[13]);
    acc[14] = fdot2_(w.y, hb.z, acc[14]);
    acc[15] = fdot2_(w.w, hb.w, acc[15]);
  }
}

// finalize-thread helper: pack 4 rows of hn (f32, one col per lane) into hq.
// lanes with (j&3)==0 write hq[j>>2][0..1]; cols j..j+3 are in the same wave.
__device__ __forceinline__ void pack_hq(uint4 (*hq)[2], int j, const float* hn){
  uint4 v0, v1;
  float b1, b2, b3;
  b1=__shfl_down(hn[0],1); b2=__shfl_down(hn[0],2); b3=__shfl_down(hn[0],3);
  v0.x = packh(hn[0], b1); v0.y = packh(b2, b3);
  b1=__shfl_down(hn[1],1); b2=__shfl_down(hn[1],2); b3=__shfl_down(hn[1],3);
  v0.z = packh(hn[1], b1); v0.w = packh(b2, b3);
  b1=__shfl_down(hn[2],1); b2=__shfl_down(hn[2],2); b3=__shfl_down(hn[2],3);
  v1.x = packh(hn[2], b1); v1.y = packh(b2, b3);
  b1=__shfl_down(hn[3],1); b2=__shfl_down(hn[3],2); b3=__shfl_down(hn[3],3);
  v1.z = packh(hn[3], b1); v1.w = packh(b2, b3);
  if ((j & 3) == 0){ hq[j>>2][0] = v0; hq[j>>2][1] = v1; }
}

__global__ __launch_bounds__(NTHR) void dag_main(
    const float* __restrict__ x,    // (T,B,NH) f32
    const float* __restrict__ h0,   // (B,NH) f32
    const float* __restrict__ bxc,  // (NH)
    const float* __restrict__ bxh,  // (NH)
    const uint32_t* __restrict__ WQ,
    float* __restrict__ out)        // T*B*NH outputs then B*NH final hidden
{
  __shared__ uint4  hq[KQ][2];      // fp16 h quads: [kq][0]={r0k01,r0k23,r1k01,r1k23}
  __shared__ uint4  xq[KQ][2];      // fp16 x quads, same layout
  __shared__ float4 part[SQ][NH][2];// k-split partials: [s][j][0]=A rows0-3, [1]=B rows0-3
  __shared__ float  red[4][BM];     // norm partials per finalize-wave

  const int tid = threadIdx.x;
  const int j   = tid & 255;
  const int s   = tid >> 8;
  const int qb  = s * QPS;
  const int r0  = blockIdx.x * BM;
  const uint4* WQ4   = (const uint4*)WQ;
  const uint4* wbase = WQ4 + (size_t)qb*NH + j;

  float hold[BM] = {0.f,0.f,0.f,0.f};
  float bc = 0.f, bh = 0.f;
  if (tid < 256){
    bc = bxc[j]; bh = bxh[j];
    #pragma unroll
    for (int r = 0; r < BM; ++r) hold[r] = h0[(size_t)(r0+r)*NH + j];
    pack_hq(hq, j, hold);
  }
  if (s == 3){
    #pragma unroll
    for (int i = 0; i < 2; ++i){
      int d  = j + i*256;
      int rr = d >> 7, kp = d & 127;
      const float2 xv = *(const float2*)&x[(size_t)(r0+rr)*NH + 2*kp];  // t=0
      int kq = kp>>1, hh = rr>>1, comp = ((rr&1)<<1) | (kp&1);
      ((uint32_t*)xq)[kq*8 + hh*4 + comp] = packh(xv.x, xv.y);
    }
  }
  __syncthreads();

  #define STORE_PART(acc) \
    part[s][j][0] = make_float4(acc[0]+acc[1],  acc[4]+acc[5],  acc[8]+acc[9],   acc[12]+acc[13]); \
    part[s][j][1] = make_float4(acc[2]+acc[3],  acc[6]+acc[7],  acc[10]+acc[11], acc[14]+acc[15]);

  #define SUM_PART(Av, Bv) \
    float Av[4] = {0,0,0,0}, Bv[4] = {0,0,0,0}; \
    _Pragma("unroll") \
    for (int ss = 0; ss < SQ; ++ss){ \
      float4 pa = part[ss][j][0], pb = part[ss][j][1]; \
      Av[0]+=pa.x; Av[1]+=pa.y; Av[2]+=pa.z; Av[3]+=pa.w; \
      Bv[0]+=pb.x; Bv[1]+=pb.y; Bv[2]+=pb.z; Bv[3]+=pb.w; \
    }

  for (int t = 0; t < T_STEPS; ++t){
    // ---- node 0: two streams (x via p=0, h via p=1) into one accumulator
    {
      float acc[16] = {};
      stream16(wbase,                    xq, qb, acc);
      stream16(wbase + (size_t)1*KQ*NH,  hq, qb, acc);
      STORE_PART(acc)
      __syncthreads();
      if (tid < 256){
        SUM_PART(Av, Bv)
        float hn[BM];
        #pragma unroll
        for (int r = 0; r < BM; ++r){
          float c = sigmoidf_(Av[r] + bc);
          float f = tanhf_(Bv[r] + bh);
          hn[r] = c*f + (1.f-c)*hold[r];
          hold[r] = hn[r];
        }
        pack_hq(hq, j, hn);
      }
      __syncthreads();
    }

    // ---- edges 0..5 (ACTS[1..6] = relu, tanh, sigmoid, identity, relu, tanh)
    #define EDGE_STAGE(P, ACT_)                                   \
    {                                                             \
      float acc[16] = {};                                         \
      stream16(wbase + (size_t)(P)*KQ*NH, hq, qb, acc);           \
      STORE_PART(acc)                                             \
      __syncthreads();                                            \
      if (tid < 256){                                             \
        SUM_PART(Av, Bv)                                          \
        float hn[BM];                                             \
        _Pragma("unroll")                                         \
        for (int r = 0; r < BM; ++r){                             \
          float c = sigmoidf_(Av[r]);                             \
          float f = actf<ACT_>(Bv[r]);                            \
          hn[r] = c*f + (1.f-c)*hold[r];                          \
          hold[r] = hn[r];                                        \
        }                                                         \
        pack_hq(hq, j, hn);                                       \
      }                                                           \
      __syncthreads();                                            \
    }

    EDGE_STAGE(2, 0)
    EDGE_STAGE(3, 1)
    EDGE_STAGE(4, 2)
    EDGE_STAGE(5, 3)
    EDGE_STAGE(6, 0)
    EDGE_STAGE(7, 1)
    #undef EDGE_STAGE

    // ---- edge 6 (identity, p=8) + norm clip + output write + xq prefetch
    {
      float acc[16] = {};
      stream16(wbase + (size_t)8*KQ*NH, hq, qb, acc);
      STORE_PART(acc)
      __syncthreads();
      float hn[BM];
      if (tid < 256){
        SUM_PART(Av, Bv)
        #pragma unroll
        for (int r = 0; r < BM; ++r){
          float c = sigmoidf_(Av[r]);
          hn[r] = c*Bv[r] + (1.f-c)*hold[r];
        }
        #pragma unroll
        for (int r = 0; r < BM; ++r){
          float pw = hn[r]*hn[r];
          #pragma unroll
          for (int off = 32; off; off >>= 1) pw += __shfl_xor(pw, off);
          if ((j & 63) == 0) red[j>>6][r] = pw;
        }
      }
      if (s == 3 && t + 1 < T_STEPS){
        #pragma unroll
        for (int i = 0; i < 2; ++i){
          int d  = j + i*256;
          int rr = d >> 7, kp = d & 127;
          const float2 xv = *(const float2*)&x[((size_t)(t+1)*B_ROWS + r0+rr)*NH + 2*kp];
          int kq = kp>>1, hh = rr>>1, comp = ((rr&1)<<1) | (kp&1);
          ((uint32_t*)xq)[kq*8 + hh*4 + comp] = packh(xv.x, xv.y);
        }
      }
      __syncthreads();
      if (tid < 256){
        #pragma unroll
        for (int r = 0; r < BM; ++r){
          float n2  = red[0][r] + red[1][r] + red[2][r] + red[3][r];
          float nrm = sqrtf(n2);
          float sc  = (nrm > 25.f) ? 25.f/nrm : 1.f;
          hn[r] *= sc;
          hold[r] = hn[r];
          out[(size_t)t*(B_ROWS*NH) + (size_t)(r0+r)*NH + j] = hn[r];
        }
        pack_hq(hq, j, hn);
      }
      __syncthreads();
    }
  }

  if (tid < 256){
    #pragma unroll
    for (int r = 0; r < BM; ++r)
      out[(size_t)T_STEPS*(B_ROWS*NH) + (size_t)(r0+r)*NH + j] = hold[r];
  }
  #undef STORE_PART
  #undef SUM_PART
}

extern "C" void kernel_launch(void* const* d_in, const int* in_sizes, int n_in,
                              void* d_out, int out_size, void* d_ws, size_t ws_size,
                              hipStream_t stream) {
  const float* x   = (const float*)d_in[0];
  const float* h0  = (const float*)d_in[1];
  const float* wxc = (const float*)d_in[2];
  const float* bxc = (const float*)d_in[3];
  const float* wxh = (const float*)d_in[4];
  const float* bxh = (const float*)d_in[5];
  const float* whc = (const float*)d_in[6];
  const float* whh = (const float*)d_in[7];
  const float* Wc  = (const float*)d_in[8];
  const float* Wh  = (const float*)d_in[9];
  uint32_t* WQ = (uint32_t*)d_ws;   // 9*64*256*4 dwords = 2.36 MB

  const int total = NPAIRS*KQ*NH*4;
  prep_weights<<<(total + 255)/256, 256, 0, stream>>>(wxc, wxh, whc, whh, Wc, Wh, WQ);
  dag_main<<<NBLK, NTHR, 0, stream>>>(x, h0, bxc, bxh, WQ, (float*)d_out);
}